// Round 1
// 21513.557 us; speedup vs baseline: 1.2720x; 1.2720x over previous
//
#include <hip/hip_runtime.h>
#include <math.h>

#define T_STEPS 512
#define IN_DIM  17
#define HID     512
#define LAT     256
#define BT      16
#define NTH     512
#define CHUNK   4

typedef __attribute__((ext_vector_type(8))) _Float16 half8;
typedef __attribute__((ext_vector_type(4))) float    f32x4;

// ---------------- workspace layout (byte offsets, 16B-aligned) ----------
#define OFF_HB0   0
#define OFF_HB1   4194304
#define OFF_LAT   8388608
#define OFF_WG    16777216
#define OFF_W2P   19136512
#define OFF_W1P   19267584
#define OFF_HEADP 19283968
#define OFF_W256  19300352
#define OFF_BCOMB 19306496
#define OFF_BHN   19312640
#define OFF_DT    19314688
#define OFF_CTR   19380224

static __device__ inline unsigned short f2h(float f) {
    union { _Float16 h; unsigned short u; } cv;
    cv.h = (_Float16)f;
    return cv.u;
}

__global__ void pack_kernel(const float* __restrict__ enc_w1,
                            const float* __restrict__ enc_w2,
                            const float* __restrict__ w_ih,
                            const float* __restrict__ w_hh,
                            const float* __restrict__ b_ih,
                            const float* __restrict__ b_hh,
                            const float* __restrict__ q_w,
                            const float* __restrict__ v_w,
                            const float* __restrict__ c_w,
                            const float* __restrict__ h0,
                            unsigned char* __restrict__ ws) {
    unsigned short* wgP   = (unsigned short*)(ws + OFF_WG);
    unsigned short* w2P   = (unsigned short*)(ws + OFF_W2P);
    unsigned short* w1P   = (unsigned short*)(ws + OFF_W1P);
    unsigned short* headP = (unsigned short*)(ws + OFF_HEADP);
    unsigned short* hb0   = (unsigned short*)(ws + OFF_HB0);
    float* w256  = (float*)(ws + OFF_W256);
    float* bcomb = (float*)(ws + OFF_BCOMB);
    float* bhn   = (float*)(ws + OFF_BHN);
    unsigned int* ctr = (unsigned int*)(ws + OFF_CTR);

    const int tid = blockIdx.x * blockDim.x + threadIdx.x;
    const int stride = gridDim.x * blockDim.x;

    for (int idx = tid; idx < 32 * 24 * 3 * 64 * 8; idx += stride) {     // wgP
        int j = idx & 7, l = (idx >> 3) & 63;
        int r = idx >> 9;
        int g = r % 3; r /= 3;
        int kt = r % 24; int s = r / 24;
        int row = g * 512 + s * 16 + (l & 15);
        int kk  = ((l >> 4) & 3) * 8 + j;
        float v;
        if (kt < 8) v = w_ih[(size_t)row * 257 + (kt * 32 + kk)];
        else        v = w_hh[(size_t)row * 512 + ((kt - 8) * 32 + kk)];
        wgP[idx] = f2h(v);
    }
    for (int idx = tid; idx < 16 * 8 * 64 * 8; idx += stride) {          // w2P
        int j = idx & 7, l = (idx >> 3) & 63, kt = (idx >> 9) & 7, nt = idx >> 12;
        int n = nt * 16 + (l & 15);
        int k = kt * 32 + ((l >> 4) & 3) * 8 + j;
        w2P[idx] = f2h(enc_w2[(size_t)n * 256 + k]);
    }
    for (int idx = tid; idx < 16 * 64 * 8; idx += stride) {              // w1P
        int j = idx & 7, l = (idx >> 3) & 63, nt = idx >> 9;
        int n = nt * 16 + (l & 15);
        int k = ((l >> 4) & 3) * 8 + j;
        w1P[idx] = (k < IN_DIM) ? f2h(enc_w1[(size_t)n * IN_DIM + k]) : (unsigned short)0;
    }
    for (int idx = tid; idx < 16 * 64 * 8; idx += stride) {              // headP
        int j = idx & 7, l = (idx >> 3) & 63, kt = idx >> 9;
        int d = l & 15;
        int k = kt * 32 + ((l >> 4) & 3) * 8 + j;
        float v = 0.f;
        if (d < 4)       v = q_w[(size_t)d * HID + k];
        else if (d < 7)  v = v_w[(size_t)(d - 4) * HID + k];
        else if (d < 10) v = c_w[(size_t)(d - 7) * HID + k];
        headP[idx] = f2h(v);
    }
    for (int idx = tid; idx < 1536; idx += stride) {
        w256[idx]  = w_ih[(size_t)idx * 257 + 256];
        bcomb[idx] = (idx < 1024) ? (b_ih[idx] + b_hh[idx]) : b_ih[idx];
    }
    for (int idx = tid; idx < 512; idx += stride) bhn[idx] = b_hh[1024 + idx];
    for (int idx = tid; idx < 4096 * 512; idx += stride)                 // h0 -> hbuf0
        hb0[idx] = f2h(h0[idx]);
    for (int idx = tid; idx < 5120; idx += stride) ctr[idx] = 0;         // barriers
}

#define MFMA16(a, b, c) __builtin_amdgcn_mfma_f32_16x16x32_f16((a), (b), (c), 0, 0, 0)

// 32-block group barrier.
// KEY CHANGE: relaxed add + relaxed spin. The previous ACQUIRE-per-poll spin
// emitted buffer_inv (L1 + L2-NC invalidate) on EVERY poll iteration -- waiting
// blocks continuously blew away the XCD's L2 while working blocks streamed their
// 24MB/step of A-operands, demoting all reuse to LLC/HBM. One release fence
// before the add and one acquire fence after the spin keep full cross-XCD
// correctness (fence-based release/acquire message passing).
static __device__ inline void group_barrier(unsigned int* slot) {
    __syncthreads();                       // all waves' vmem drained (implied waitcnt)
    if (threadIdx.x == 0) {
        __threadfence();                   // release (single wbl2)
        __hip_atomic_fetch_add(slot, 1u, __ATOMIC_RELAXED, __HIP_MEMORY_SCOPE_AGENT);
        while (__hip_atomic_load(slot, __ATOMIC_RELAXED, __HIP_MEMORY_SCOPE_AGENT) < 32u)
            __builtin_amdgcn_s_sleep(2);
        __threadfence();                   // acquire (single invalidate per step)
    }
    __syncthreads();
}

__global__ __launch_bounds__(NTH, 2)
void imu_coop_kernel(const float* __restrict__ x,
                     const float* __restrict__ h0,
                     const float* __restrict__ enc_b1,
                     const float* __restrict__ enc_b2,
                     const float* __restrict__ q_b,
                     const float* __restrict__ v_b,
                     const float* __restrict__ c_b,
                     unsigned char* __restrict__ ws,
                     float* __restrict__ out)
{
    __shared__ __align__(16) unsigned short wgL[24 * 3 * 64 * 8];   // 73,728 B
    __shared__ __align__(16) unsigned short headL[16 * 64 * 8];     // 16,384 B
    __shared__ __align__(16) unsigned short xbf64[64][32];          //  4,096 B
    __shared__ __align__(16) unsigned short z1bf64[64][264];        // 33,792 B
    __shared__ __align__(16) float          sdotP[8][16][17];       //  8,704 B
    __shared__ float eb1L[256], eb2L[256];                          //  2,048 B
    __shared__ float dtL[512][4];                                   //  8,192 B
    __shared__ float xownL[2][4][16][4];                            //  2,048 B

    unsigned short* hb[2] = { (unsigned short*)(ws + OFF_HB0),
                              (unsigned short*)(ws + OFF_HB1) };
    unsigned short*       latbuf = (unsigned short*)(ws + OFF_LAT);
    const unsigned short* wgP    = (const unsigned short*)(ws + OFF_WG);
    const unsigned short* w2P    = (const unsigned short*)(ws + OFF_W2P);
    const unsigned short* w1P    = (const unsigned short*)(ws + OFF_W1P);
    const unsigned short* headP  = (const unsigned short*)(ws + OFF_HEADP);
    const float* w256g = (const float*)(ws + OFF_W256);
    const float* bcmg  = (const float*)(ws + OFF_BCOMB);
    const float* bhng  = (const float*)(ws + OFF_BHN);
    float* dtbuf = (float*)(ws + OFF_DT);
    unsigned int* stepctr  = (unsigned int*)(ws + OFF_CTR) + (size_t)(blockIdx.x & 7) * 512;
    unsigned int* chunkctr = (unsigned int*)(ws + OFF_CTR + 16384) + (size_t)(blockIdx.x & 7) * 128;

    const int t    = threadIdx.x;
    const int w    = t >> 6;
    const int l    = t & 63;
    const int l15  = l & 15;
    const int lq   = (l >> 4) & 3;
    const int s_sl = blockIdx.x >> 3;            // gate N-slice 0..31
    const int g    = blockIdx.x & 7;             // batch group 0..7
    const int eb0  = g * 512 + s_sl * 16;        // encoder/heads rows (inside group!)

    const f32x4 fz = {0.f, 0.f, 0.f, 0.f};

    // ---- one-time init ----
    {
        const uint4* src = (const uint4*)(wgP + (size_t)s_sl * (24 * 3 * 64 * 8));
        uint4* dst = (uint4*)wgL;
        for (int i = t; i < 24 * 3 * 64; i += NTH) dst[i] = src[i];
    }
    {
        const uint4* src = (const uint4*)headP;
        uint4* dst = (uint4*)headL;
        for (int i = t; i < 16 * 64; i += NTH) dst[i] = src[i];
    }
    for (int idx = t; idx < 256; idx += NTH) { eb1L[idx] = enc_b1[idx]; eb2L[idx] = enc_b2[idx]; }
    for (int idx = t; idx < 64 * 32; idx += NTH) xbf64[idx >> 5][idx & 31] = 0;

    // head biases once into registers (uniform -> SGPRs)
    const float qb0 = q_b[0], qb1 = q_b[1], qb2 = q_b[2], qb3 = q_b[3];
    const float vb0 = v_b[0], vb1 = v_b[1], vb2 = v_b[2];
    const float cb0 = c_b[0], cb1 = c_b[1], cb2 = c_b[2];

    const int jd = s_sl * 16 + l15;              // owned gate/h dim
    const float bR  = bcmg[jd],        bZ  = bcmg[512 + jd];
    const float bIN = bcmg[1024 + jd], bHN = bhng[jd];
    const float wr2 = w256g[jd], wz2 = w256g[512 + jd], wn2 = w256g[1024 + jd];

    float ho[4][4];                              // h_old fp32 in regs
    #pragma unroll
    for (int mt = 0; mt < 4; ++mt)
        #pragma unroll
        for (int i = 0; i < 4; ++i)
            ho[mt][i] = h0[(size_t)(g * 512 + w * 64 + mt * 16 + lq * 4 + i) * HID + jd];

    float dp0 = 0.f, dp1 = 0.f, dp2 = 0.f;
    __syncthreads();

    const size_t r0 = (size_t)(g * 512 + w * 64) + l15;   // A-frag row base (+mt*16)

#define LDA(dst, ktv)                                                           \
            { _Pragma("unroll")                                                 \
              for (int mt = 0; mt < 4; ++mt)                                    \
                  dst[mt] = ((ktv) < 8)                                         \
                    ? *(const half8*)(latp + (size_t)mt * (16 * 4 * 256) + (ktv) * 32)      \
                    : *(const half8*)(hp   + (size_t)mt * (16 * 512) + ((ktv) - 8) * 32); }
#define LDB(dst, ktv)                                                           \
            { _Pragma("unroll")                                                 \
              for (int gg = 0; gg < 3; ++gg)                                    \
                  dst[gg] = *(const half8*)&wgL[(((ktv) * 3 + gg) * 64 + l) * 8]; }
#define DOMF(A, B, ktv)                                                         \
            { _Pragma("unroll")                                                 \
              for (int mt = 0; mt < 4; ++mt) {                                  \
                  aR[mt] = MFMA16(A[mt], B[0], aR[mt]);                         \
                  aZ[mt] = MFMA16(A[mt], B[1], aZ[mt]);                         \
                  if ((ktv) < 8) aNi[mt] = MFMA16(A[mt], B[2], aNi[mt]);        \
                  else           aNh[mt] = MFMA16(A[mt], B[2], aNh[mt]); } }

    for (int s = 0; s < T_STEPS; ++s) {
        const int cs = s & 3;
        // ================= lat pre-phase, once per 4 steps =================
        if (cs == 0) {
            const int c = s >> 2;
            for (int idx = t; idx < 17 * 16 * CHUNK; idx += NTH) {
                int k = idx % 17, rem = idx / 17;
                int b = rem & 15, cc = rem >> 4;
                float v = x[((size_t)(eb0 + b) * T_STEPS + (c * 4 + cc)) * IN_DIM + k];
                xbf64[cc * 16 + b][k] = f2h(v);
                if (k < 3) xownL[c & 1][cc][b][k] = v;       // f32 acc for heads tail
                if (k == 16) {
                    dtbuf[(size_t)(eb0 + b) * 4 + cc] = v;
                    xownL[c & 1][cc][b][3] = v;              // f32 dt for heads tail
                }
            }
            __syncthreads();
            {   // E1: M=64 (16 batch x 4 steps), N=256, K=32
                const int nt0 = 2 * w, nt1 = 2 * w + 1;
                half8 bv0 = *(const half8*)(w1P + ((size_t)nt0 * 64 + l) * 8);
                half8 bv1 = *(const half8*)(w1P + ((size_t)nt1 * 64 + l) * 8);
                f32x4 e[4][2];
                #pragma unroll
                for (int mt = 0; mt < 4; ++mt) {
                    half8 av = *(const half8*)&xbf64[mt * 16 + l15][lq * 8];
                    e[mt][0] = MFMA16(av, bv0, fz);
                    e[mt][1] = MFMA16(av, bv1, fz);
                }
                __syncthreads();
                #pragma unroll
                for (int mt = 0; mt < 4; ++mt)
                    #pragma unroll
                    for (int i = 0; i < 4; ++i) {
                        int m64 = mt * 16 + lq * 4 + i;
                        int n0 = nt0 * 16 + l15, n1 = nt1 * 16 + l15;
                        z1bf64[m64][n0] = f2h(fmaxf(e[mt][0][i] + eb1L[n0], 0.f));
                        z1bf64[m64][n1] = f2h(fmaxf(e[mt][1][i] + eb1L[n1], 0.f));
                    }
            }
            __syncthreads();
            {   // E2: M=64, N=256, K=256 -> latbuf (global)
                const int nt0 = 2 * w, nt1 = 2 * w + 1;
                f32x4 e[4][2];
                #pragma unroll
                for (int mt = 0; mt < 4; ++mt) { e[mt][0] = fz; e[mt][1] = fz; }
                #pragma unroll
                for (int kt = 0; kt < 8; ++kt) {
                    half8 bv0 = *(const half8*)(w2P + ((size_t)(nt0 * 8 + kt) * 64 + l) * 8);
                    half8 bv1 = *(const half8*)(w2P + ((size_t)(nt1 * 8 + kt) * 64 + l) * 8);
                    #pragma unroll
                    for (int mt = 0; mt < 4; ++mt) {
                        half8 av = *(const half8*)&z1bf64[mt * 16 + l15][kt * 32 + lq * 8];
                        e[mt][0] = MFMA16(av, bv0, e[mt][0]);
                        e[mt][1] = MFMA16(av, bv1, e[mt][1]);
                    }
                }
                #pragma unroll
                for (int mt = 0; mt < 4; ++mt)
                    #pragma unroll
                    for (int i = 0; i < 4; ++i) {
                        int b = lq * 4 + i;      // batch-in-16 ; cc = mt
                        int n0 = nt0 * 16 + l15, n1 = nt1 * 16 + l15;
                        size_t rb = ((size_t)(eb0 + b) * 4 + mt) * 256;
                        latbuf[rb + n0] = f2h(fmaxf(e[mt][0][i] + eb2L[n0], 0.f));
                        latbuf[rb + n1] = f2h(fmaxf(e[mt][1][i] + eb2L[n1], 0.f));
                    }
            }
            group_barrier(&chunkctr[c]);
            {   // stage whole group's dt for this chunk into LDS (coalesced)
                const float* srcdt = dtbuf + (size_t)g * 2048;
                float* dstdt = &dtL[0][0];
                for (int idx = t; idx < 2048; idx += NTH) dstdt[idx] = srcdt[idx];
            }
            __syncthreads();
        }

        const int rp = s & 1, wp = rp ^ 1;
        const unsigned short* hrd = hb[rp];
        unsigned short*       hwr = hb[wp];

        const unsigned short* latp = latbuf + (r0 * 4 + cs) * 256 + lq * 8;
        const unsigned short* hp   = hrd + r0 * 512 + lq * 8;

        // ---- gate GEMM prologue: issue depth-3 A loads early so they fly
        //      under the heads phase (the heads __syncthreads drains them) ----
        half8 aF[3][4], bF[2][3];
        LDA(aF[0], 0); LDA(aF[1], 1); LDA(aF[2], 2);
        LDB(bF[0], 0); LDB(bF[1], 1);

        // ================= heads(s-1) + dp(s-1) =================
        if (s > 0) {
            f32x4 hc = fz;
            const int ka = 2 * w, kb = 2 * w + 1;
            half8 a0 = *(const half8*)(hrd + (size_t)(eb0 + l15) * 512 + ka * 32 + lq * 8);
            half8 b0 = *(const half8*)(headL + ((size_t)ka * 64 + l) * 8);
            half8 a1 = *(const half8*)(hrd + (size_t)(eb0 + l15) * 512 + kb * 32 + lq * 8);
            half8 b1 = *(const half8*)(headL + ((size_t)kb * 64 + l) * 8);
            hc = MFMA16(a0, b0, hc);
            hc = MFMA16(a1, b1, hc);
            #pragma unroll
            for (int i = 0; i < 4; ++i) sdotP[w][lq * 4 + i][l15] = hc[i];
            __syncthreads();
            if (t < BT) {
                const int b = t;
                float sd[10];
                #pragma unroll
                for (int d = 0; d < 10; ++d) {
                    float acc = 0.f;
                    #pragma unroll
                    for (int w8 = 0; w8 < 8; ++w8) acc += sdotP[w8][b][d];
                    sd[d] = acc;
                }
                const int ps = s - 1, pcc = ps & 3, ppar = (ps >> 2) & 1;
                float ax = xownL[ppar][pcc][b][0], ay = xownL[ppar][pcc][b][1];
                float az = xownL[ppar][pcc][b][2], dtv = xownL[ppar][pcc][b][3];
                float q0 = sd[0] + qb0, q1 = sd[1] + qb1;
                float q2 = sd[2] + qb2, q3 = sd[3] + qb3;
                float nrm = fmaxf(sqrtf(q0*q0 + q1*q1 + q2*q2 + q3*q3), 1e-12f);
                float qw = q0/nrm, qx = q1/nrm, qy = q2/nrm, qz = q3/nrm;
                float vx = sd[4] + vb0, vy = sd[5] + vb1, vz = sd[6] + vb2;
                float ex = sd[7] + cb0, ey = sd[8] + cb1, ez = sd[9] + cb2;
                float xx = qx*qx, yy = qy*qy, zz = qz*qz;
                float xy = qx*qy, xz = qx*qz, yz = qy*qz;
                float wxq = qw*qx, wyq = qw*qy, wzq = qw*qz;
                float aw0 = (1.f - 2.f*(yy+zz))*ax + 2.f*(xy-wzq)*ay + 2.f*(xz+wyq)*az;
                float aw1 = 2.f*(xy+wzq)*ax + (1.f - 2.f*(xx+zz))*ay + 2.f*(yz-wxq)*az;
                float aw2 = 2.f*(xz-wyq)*ax + 2.f*(yz+wxq)*ay + (1.f - 2.f*(xx+yy))*az;
                float hdt2 = 0.5f * dtv * dtv;
                dp0 += vx*dtv + aw0*hdt2 + ex;
                dp1 += vy*dtv + aw1*hdt2 + ey;
                dp2 += vz*dtv + aw2*hdt2 + ez;
            }
        }

        // ================= gate GEMM: M=512, N=48, K=768 =================
        {
            f32x4 aR[4], aZ[4], aNi[4], aNh[4];
            #pragma unroll
            for (int mt = 0; mt < 4; ++mt) {
                aR[mt] = fz; aZ[mt] = fz; aNi[mt] = fz; aNh[mt] = fz;
            }
            // depth-3 rotating A pipeline (global, ~300-900cy), depth-2 B (LDS)
            #pragma unroll
            for (int kt = 0; kt < 24; ++kt) {
                DOMF(aF[kt % 3], bF[kt & 1], kt);
                if (kt < 21) LDA(aF[kt % 3], kt + 3);
                if (kt < 22) LDB(bF[kt & 1], kt + 2);
            }
            // gate nonlinearity + h_new write
            #pragma unroll
            for (int mt = 0; mt < 4; ++mt) {
                #pragma unroll
                for (int i = 0; i < 4; ++i) {
                    const int  rl  = w * 64 + mt * 16 + lq * 4 + i;   // row in group
                    const size_t row = (size_t)(g * 512) + rl;
                    float dtv = dtL[rl][cs];
                    float gr = aR[mt][i]  + bR  + dtv * wr2;
                    float gz = aZ[mt][i]  + bZ  + dtv * wz2;
                    float gi = aNi[mt][i] + bIN + dtv * wn2;
                    float gh = aNh[mt][i] + bHN;
                    float r  = 1.f / (1.f + __expf(-gr));
                    float zg = 1.f / (1.f + __expf(-gz));
                    float narg = gi + r * gh;
                    float n  = 1.f - 2.f / (__expf(2.f * narg) + 1.f);
                    float hn = (1.f - zg) * n + zg * ho[mt][i];
                    ho[mt][i] = hn;
                    hwr[row * 512 + jd] = f2h(hn);
                }
            }
        }
        group_barrier(&stepctr[s]);
    }
#undef LDA
#undef LDB
#undef DOMF

    // ================= epilogue: heads(T-1) + dp(T-1) + store =================
    {
        const unsigned short* hrd = hb[T_STEPS & 1];
        f32x4 hc = fz;
        const int ka = 2 * w, kb = 2 * w + 1;
        half8 a0 = *(const half8*)(hrd + (size_t)(eb0 + l15) * 512 + ka * 32 + lq * 8);
        half8 b0 = *(const half8*)(headL + ((size_t)ka * 64 + l) * 8);
        half8 a1 = *(const half8*)(hrd + (size_t)(eb0 + l15) * 512 + kb * 32 + lq * 8);
        half8 b1 = *(const half8*)(headL + ((size_t)kb * 64 + l) * 8);
        hc = MFMA16(a0, b0, hc);
        hc = MFMA16(a1, b1, hc);
        #pragma unroll
        for (int i = 0; i < 4; ++i) sdotP[w][lq * 4 + i][l15] = hc[i];
    }
    __syncthreads();
    if (t < BT) {
        const int b = t;
        float sd[10];
        #pragma unroll
        for (int d = 0; d < 10; ++d) {
            float acc = 0.f;
            #pragma unroll
            for (int w8 = 0; w8 < 8; ++w8) acc += sdotP[w8][b][d];
            sd[d] = acc;
        }
        const int pcc = (T_STEPS - 1) & 3, ppar = ((T_STEPS - 1) >> 2) & 1;
        float ax = xownL[ppar][pcc][b][0], ay = xownL[ppar][pcc][b][1];
        float az = xownL[ppar][pcc][b][2], dtv = xownL[ppar][pcc][b][3];
        float q0 = sd[0] + qb0, q1 = sd[1] + qb1;
        float q2 = sd[2] + qb2, q3 = sd[3] + qb3;
        float nrm = fmaxf(sqrtf(q0*q0 + q1*q1 + q2*q2 + q3*q3), 1e-12f);
        float qw = q0/nrm, qx = q1/nrm, qy = q2/nrm, qz = q3/nrm;
        float vx = sd[4] + vb0, vy = sd[5] + vb1, vz = sd[6] + vb2;
        float ex = sd[7] + cb0, ey = sd[8] + cb1, ez = sd[9] + cb2;
        float xx = qx*qx, yy = qy*qy, zz = qz*qz;
        float xy = qx*qy, xz = qx*qz, yz = qy*qz;
        float wxq = qw*qx, wyq = qw*qy, wzq = qw*qz;
        float aw0 = (1.f - 2.f*(yy+zz))*ax + 2.f*(xy-wzq)*ay + 2.f*(xz+wyq)*az;
        float aw1 = 2.f*(xy+wzq)*ax + (1.f - 2.f*(xx+zz))*ay + 2.f*(yz-wxq)*az;
        float aw2 = 2.f*(xz-wyq)*ax + 2.f*(yz+wxq)*ay + (1.f - 2.f*(xx+yy))*az;
        float hdt2 = 0.5f * dtv * dtv;
        dp0 += vx*dtv + aw0*hdt2 + ex;
        dp1 += vy*dtv + aw1*hdt2 + ey;
        dp2 += vz*dtv + aw2*hdt2 + ez;
        out[(size_t)(eb0 + b) * 3 + 0] = dp0;
        out[(size_t)(eb0 + b) * 3 + 1] = dp1;
        out[(size_t)(eb0 + b) * 3 + 2] = dp2;
    }
}

extern "C" void kernel_launch(void* const* d_in, const int* in_sizes, int n_in,
                              void* d_out, int out_size, void* d_ws, size_t ws_size,
                              hipStream_t stream) {
    const float* x      = (const float*)d_in[0];
    const float* h0     = (const float*)d_in[1];
    const float* enc_w1 = (const float*)d_in[2];
    const float* enc_b1 = (const float*)d_in[3];
    const float* enc_w2 = (const float*)d_in[4];
    const float* enc_b2 = (const float*)d_in[5];
    const float* w_ih   = (const float*)d_in[6];
    const float* w_hh   = (const float*)d_in[7];
    const float* b_ih   = (const float*)d_in[8];
    const float* b_hh   = (const float*)d_in[9];
    const float* q_w    = (const float*)d_in[10];
    const float* q_b    = (const float*)d_in[11];
    const float* v_w    = (const float*)d_in[12];
    const float* v_b    = (const float*)d_in[13];
    const float* c_w    = (const float*)d_in[14];
    const float* c_b    = (const float*)d_in[15];
    unsigned char* ws = (unsigned char*)d_ws;
    float* out = (float*)d_out;

    hipLaunchKernelGGL(pack_kernel, dim3(2048), dim3(256), 0, stream,
                       enc_w1, enc_w2, w_ih, w_hh, b_ih, b_hh, q_w, v_w, c_w, h0, ws);

    void* args[] = { (void*)&x, (void*)&h0, (void*)&enc_b1, (void*)&enc_b2,
                     (void*)&q_b, (void*)&v_b, (void*)&c_b, (void*)&ws, (void*)&out };
    (void)hipLaunchCooperativeKernel((void*)imu_coop_kernel, dim3(256), dim3(NTH),
                                     args, 0, stream);
}

// Round 2
// 15576.309 us; speedup vs baseline: 1.7569x; 1.3812x over previous
//
#include <hip/hip_runtime.h>
#include <math.h>

#define T_STEPS 512
#define IN_DIM  17
#define HID     512
#define LAT     256
#define BT      16
#define NTH     512
#define CHUNK   4

typedef __attribute__((ext_vector_type(8))) _Float16 half8;
typedef __attribute__((ext_vector_type(4))) float    f32x4;

// ---------------- workspace layout (byte offsets, 16B-aligned) ----------
#define OFF_HB0   0
#define OFF_HB1   4194304
#define OFF_LAT   8388608
#define OFF_WG    16777216
#define OFF_W2P   19136512
#define OFF_W1P   19267584
#define OFF_HEADP 19283968
#define OFF_W256  19300352
#define OFF_BCOMB 19306496
#define OFF_BHN   19312640
#define OFF_DT    19314688
#define OFF_CTR   19380224
// ctr region: stepctr uint[8][512] + chunkctr uint[8][128] + ticket uint[8]

static __device__ inline unsigned short f2h(float f) {
    union { _Float16 h; unsigned short u; } cv;
    cv.h = (_Float16)f;
    return cv.u;
}

__global__ void pack_kernel(const float* __restrict__ enc_w1,
                            const float* __restrict__ enc_w2,
                            const float* __restrict__ w_ih,
                            const float* __restrict__ w_hh,
                            const float* __restrict__ b_ih,
                            const float* __restrict__ b_hh,
                            const float* __restrict__ q_w,
                            const float* __restrict__ v_w,
                            const float* __restrict__ c_w,
                            const float* __restrict__ h0,
                            unsigned char* __restrict__ ws) {
    unsigned short* wgP   = (unsigned short*)(ws + OFF_WG);
    unsigned short* w2P   = (unsigned short*)(ws + OFF_W2P);
    unsigned short* w1P   = (unsigned short*)(ws + OFF_W1P);
    unsigned short* headP = (unsigned short*)(ws + OFF_HEADP);
    unsigned short* hb0   = (unsigned short*)(ws + OFF_HB0);
    float* w256  = (float*)(ws + OFF_W256);
    float* bcomb = (float*)(ws + OFF_BCOMB);
    float* bhn   = (float*)(ws + OFF_BHN);
    unsigned int* ctr = (unsigned int*)(ws + OFF_CTR);

    const int tid = blockIdx.x * blockDim.x + threadIdx.x;
    const int stride = gridDim.x * blockDim.x;

    for (int idx = tid; idx < 32 * 24 * 3 * 64 * 8; idx += stride) {     // wgP
        int j = idx & 7, l = (idx >> 3) & 63;
        int r = idx >> 9;
        int g = r % 3; r /= 3;
        int kt = r % 24; int s = r / 24;
        int row = g * 512 + s * 16 + (l & 15);
        int kk  = ((l >> 4) & 3) * 8 + j;
        float v;
        if (kt < 8) v = w_ih[(size_t)row * 257 + (kt * 32 + kk)];
        else        v = w_hh[(size_t)row * 512 + ((kt - 8) * 32 + kk)];
        wgP[idx] = f2h(v);
    }
    for (int idx = tid; idx < 16 * 8 * 64 * 8; idx += stride) {          // w2P
        int j = idx & 7, l = (idx >> 3) & 63, kt = (idx >> 9) & 7, nt = idx >> 12;
        int n = nt * 16 + (l & 15);
        int k = kt * 32 + ((l >> 4) & 3) * 8 + j;
        w2P[idx] = f2h(enc_w2[(size_t)n * 256 + k]);
    }
    for (int idx = tid; idx < 16 * 64 * 8; idx += stride) {              // w1P
        int j = idx & 7, l = (idx >> 3) & 63, nt = idx >> 9;
        int n = nt * 16 + (l & 15);
        int k = ((l >> 4) & 3) * 8 + j;
        w1P[idx] = (k < IN_DIM) ? f2h(enc_w1[(size_t)n * IN_DIM + k]) : (unsigned short)0;
    }
    for (int idx = tid; idx < 16 * 64 * 8; idx += stride) {              // headP
        int j = idx & 7, l = (idx >> 3) & 63, kt = idx >> 9;
        int d = l & 15;
        int k = kt * 32 + ((l >> 4) & 3) * 8 + j;
        float v = 0.f;
        if (d < 4)       v = q_w[(size_t)d * HID + k];
        else if (d < 7)  v = v_w[(size_t)(d - 4) * HID + k];
        else if (d < 10) v = c_w[(size_t)(d - 7) * HID + k];
        headP[idx] = f2h(v);
    }
    for (int idx = tid; idx < 1536; idx += stride) {
        w256[idx]  = w_ih[(size_t)idx * 257 + 256];
        bcomb[idx] = (idx < 1024) ? (b_ih[idx] + b_hh[idx]) : b_ih[idx];
    }
    for (int idx = tid; idx < 512; idx += stride) bhn[idx] = b_hh[1024 + idx];
    for (int idx = tid; idx < 4096 * 512; idx += stride)                 // h0 -> hbuf0
        hb0[idx] = f2h(h0[idx]);
    for (int idx = tid; idx < 5128; idx += stride) ctr[idx] = 0;         // barriers + tickets
}

#define MFMA16(a, b, c) __builtin_amdgcn_mfma_f32_16x16x32_f16((a), (b), (c), 0, 0, 0)

// 32-block XCD-local group barrier.
// Groups are pinned to one physical XCD (g = HW_REG_XCC_ID, see below), so the
// XCD's shared L2 is the coherence point:
//   release = the vmcnt(0) drain implied by __syncthreads (L1 is write-through,
//             stores are in L2 once retired) -- NO buffer_wbl2.
//   acquire = L1-only invalidate (buffer_inv sc0), executed by every wave
//             after the spin completes -- NO L2 invalidate, no LLC refill.
// The counter itself is an agent-scope relaxed RMW/poll (executes at the
// coherence fabric; no cache maintenance attached).
static __device__ inline void xcd_barrier(unsigned int* slot) {
    __syncthreads();                       // all waves' stores drained to L2
    if (threadIdx.x == 0) {
        __hip_atomic_fetch_add(slot, 1u, __ATOMIC_RELAXED, __HIP_MEMORY_SCOPE_AGENT);
        while (__hip_atomic_load(slot, __ATOMIC_RELAXED, __HIP_MEMORY_SCOPE_AGENT) < 32u)
            __builtin_amdgcn_s_sleep(2);
    }
    __syncthreads();
    asm volatile("buffer_inv sc0" ::: "memory");   // per-wave L1 invalidate
}

__global__ __launch_bounds__(NTH, 2)
void imu_coop_kernel(const float* __restrict__ x,
                     const float* __restrict__ h0,
                     const float* __restrict__ enc_b1,
                     const float* __restrict__ enc_b2,
                     const float* __restrict__ q_b,
                     const float* __restrict__ v_b,
                     const float* __restrict__ c_b,
                     unsigned char* __restrict__ ws,
                     float* __restrict__ out)
{
    __shared__ __align__(16) unsigned short wgL[24 * 3 * 64 * 8];   // 73,728 B
    __shared__ __align__(16) unsigned short headL[16 * 64 * 8];     // 16,384 B
    __shared__ __align__(16) unsigned short xbf64[64][32];          //  4,096 B
    __shared__ __align__(16) unsigned short z1bf64[64][264];        // 33,792 B
    __shared__ __align__(16) float          sdotP[8][16][17];       //  8,704 B
    __shared__ float eb1L[256], eb2L[256];                          //  2,048 B
    __shared__ float dtL[512][4];                                   //  8,192 B
    __shared__ float xownL[2][4][16][4];                            //  2,048 B
    __shared__ int   s_slS;

    unsigned short* hb[2] = { (unsigned short*)(ws + OFF_HB0),
                              (unsigned short*)(ws + OFF_HB1) };
    unsigned short*       latbuf = (unsigned short*)(ws + OFF_LAT);
    const unsigned short* wgP    = (const unsigned short*)(ws + OFF_WG);
    const unsigned short* w2P    = (const unsigned short*)(ws + OFF_W2P);
    const unsigned short* w1P    = (const unsigned short*)(ws + OFF_W1P);
    const unsigned short* headP  = (const unsigned short*)(ws + OFF_HEADP);
    const float* w256g = (const float*)(ws + OFF_W256);
    const float* bcmg  = (const float*)(ws + OFF_BCOMB);
    const float* bhng  = (const float*)(ws + OFF_BHN);
    float* dtbuf = (float*)(ws + OFF_DT);

    const int t    = threadIdx.x;
    const int w    = t >> 6;
    const int l    = t & 63;
    const int l15  = l & 15;
    const int lq   = (l >> 4) & 3;

    // ---- XCD-local self-assignment: group = physical XCD, slice = ticket ----
    // LDS 149KB forces 1 block/CU; cooperative launch co-residency on 256 CUs
    // => exactly 32 blocks per XCD, so tickets 0..31 and groups are XCD-local
    // BY CONSTRUCTION (no assumption about blockIdx->XCD mapping).
    unsigned int xcc;
    asm volatile("s_getreg_b32 %0, hwreg(HW_REG_XCC_ID)" : "=s"(xcc));
    const int g = (int)(xcc & 7u);
    if (t == 0) {
        unsigned int* tk = (unsigned int*)(ws + OFF_CTR) + 5120 + g;
        s_slS = (int)(__hip_atomic_fetch_add(tk, 1u, __ATOMIC_RELAXED,
                                             __HIP_MEMORY_SCOPE_AGENT) & 31u);
    }
    __syncthreads();
    const int s_sl = s_slS;                      // gate N-slice 0..31
    const int eb0  = g * 512 + s_sl * 16;        // encoder/heads rows (inside group!)

    unsigned int* stepctr  = (unsigned int*)(ws + OFF_CTR) + (size_t)g * 512;
    unsigned int* chunkctr = (unsigned int*)(ws + OFF_CTR + 16384) + (size_t)g * 128;

    const f32x4 fz = {0.f, 0.f, 0.f, 0.f};

    // ---- one-time init ----
    {
        const uint4* src = (const uint4*)(wgP + (size_t)s_sl * (24 * 3 * 64 * 8));
        uint4* dst = (uint4*)wgL;
        for (int i = t; i < 24 * 3 * 64; i += NTH) dst[i] = src[i];
    }
    {
        const uint4* src = (const uint4*)headP;
        uint4* dst = (uint4*)headL;
        for (int i = t; i < 16 * 64; i += NTH) dst[i] = src[i];
    }
    for (int idx = t; idx < 256; idx += NTH) { eb1L[idx] = enc_b1[idx]; eb2L[idx] = enc_b2[idx]; }
    for (int idx = t; idx < 64 * 32; idx += NTH) xbf64[idx >> 5][idx & 31] = 0;

    // head biases once into registers (uniform -> SGPRs)
    const float qb0 = q_b[0], qb1 = q_b[1], qb2 = q_b[2], qb3 = q_b[3];
    const float vb0 = v_b[0], vb1 = v_b[1], vb2 = v_b[2];
    const float cb0 = c_b[0], cb1 = c_b[1], cb2 = c_b[2];

    const int jd = s_sl * 16 + l15;              // owned gate/h dim
    const float bR  = bcmg[jd],        bZ  = bcmg[512 + jd];
    const float bIN = bcmg[1024 + jd], bHN = bhng[jd];
    const float wr2 = w256g[jd], wz2 = w256g[512 + jd], wn2 = w256g[1024 + jd];

    float ho[4][4];                              // h_old fp32 in regs
    #pragma unroll
    for (int mt = 0; mt < 4; ++mt)
        #pragma unroll
        for (int i = 0; i < 4; ++i)
            ho[mt][i] = h0[(size_t)(g * 512 + w * 64 + mt * 16 + lq * 4 + i) * HID + jd];

    float dp0 = 0.f, dp1 = 0.f, dp2 = 0.f;
    __syncthreads();

    const size_t r0 = (size_t)(g * 512 + w * 64) + l15;   // A-frag row base (+mt*16)

#define LDA(dst, ktv)                                                           \
            { _Pragma("unroll")                                                 \
              for (int mt = 0; mt < 4; ++mt)                                    \
                  dst[mt] = ((ktv) < 8)                                         \
                    ? *(const half8*)(latp + (size_t)mt * (16 * 4 * 256) + (ktv) * 32)      \
                    : *(const half8*)(hp   + (size_t)mt * (16 * 512) + ((ktv) - 8) * 32); }
#define LDB(dst, ktv)                                                           \
            { _Pragma("unroll")                                                 \
              for (int gg = 0; gg < 3; ++gg)                                    \
                  dst[gg] = *(const half8*)&wgL[(((ktv) * 3 + gg) * 64 + l) * 8]; }
#define DOMF(A, B, ktv)                                                         \
            { _Pragma("unroll")                                                 \
              for (int mt = 0; mt < 4; ++mt) {                                  \
                  aR[mt] = MFMA16(A[mt], B[0], aR[mt]);                         \
                  aZ[mt] = MFMA16(A[mt], B[1], aZ[mt]);                         \
                  if ((ktv) < 8) aNi[mt] = MFMA16(A[mt], B[2], aNi[mt]);        \
                  else           aNh[mt] = MFMA16(A[mt], B[2], aNh[mt]); } }

    for (int s = 0; s < T_STEPS; ++s) {
        const int cs = s & 3;
        // ================= lat pre-phase, once per 4 steps =================
        if (cs == 0) {
            const int c = s >> 2;
            for (int idx = t; idx < 17 * 16 * CHUNK; idx += NTH) {
                int k = idx % 17, rem = idx / 17;
                int b = rem & 15, cc = rem >> 4;
                float v = x[((size_t)(eb0 + b) * T_STEPS + (c * 4 + cc)) * IN_DIM + k];
                xbf64[cc * 16 + b][k] = f2h(v);
                if (k < 3) xownL[c & 1][cc][b][k] = v;       // f32 acc for heads tail
                if (k == 16) {
                    dtbuf[(size_t)(eb0 + b) * 4 + cc] = v;
                    xownL[c & 1][cc][b][3] = v;              // f32 dt for heads tail
                }
            }
            __syncthreads();
            {   // E1: M=64 (16 batch x 4 steps), N=256, K=32
                const int nt0 = 2 * w, nt1 = 2 * w + 1;
                half8 bv0 = *(const half8*)(w1P + ((size_t)nt0 * 64 + l) * 8);
                half8 bv1 = *(const half8*)(w1P + ((size_t)nt1 * 64 + l) * 8);
                f32x4 e[4][2];
                #pragma unroll
                for (int mt = 0; mt < 4; ++mt) {
                    half8 av = *(const half8*)&xbf64[mt * 16 + l15][lq * 8];
                    e[mt][0] = MFMA16(av, bv0, fz);
                    e[mt][1] = MFMA16(av, bv1, fz);
                }
                __syncthreads();
                #pragma unroll
                for (int mt = 0; mt < 4; ++mt)
                    #pragma unroll
                    for (int i = 0; i < 4; ++i) {
                        int m64 = mt * 16 + lq * 4 + i;
                        int n0 = nt0 * 16 + l15, n1 = nt1 * 16 + l15;
                        z1bf64[m64][n0] = f2h(fmaxf(e[mt][0][i] + eb1L[n0], 0.f));
                        z1bf64[m64][n1] = f2h(fmaxf(e[mt][1][i] + eb1L[n1], 0.f));
                    }
            }
            __syncthreads();
            {   // E2: M=64, N=256, K=256 -> latbuf (global)
                const int nt0 = 2 * w, nt1 = 2 * w + 1;
                f32x4 e[4][2];
                #pragma unroll
                for (int mt = 0; mt < 4; ++mt) { e[mt][0] = fz; e[mt][1] = fz; }
                #pragma unroll
                for (int kt = 0; kt < 8; ++kt) {
                    half8 bv0 = *(const half8*)(w2P + ((size_t)(nt0 * 8 + kt) * 64 + l) * 8);
                    half8 bv1 = *(const half8*)(w2P + ((size_t)(nt1 * 8 + kt) * 64 + l) * 8);
                    #pragma unroll
                    for (int mt = 0; mt < 4; ++mt) {
                        half8 av = *(const half8*)&z1bf64[mt * 16 + l15][kt * 32 + lq * 8];
                        e[mt][0] = MFMA16(av, bv0, e[mt][0]);
                        e[mt][1] = MFMA16(av, bv1, e[mt][1]);
                    }
                }
                #pragma unroll
                for (int mt = 0; mt < 4; ++mt)
                    #pragma unroll
                    for (int i = 0; i < 4; ++i) {
                        int b = lq * 4 + i;      // batch-in-16 ; cc = mt
                        int n0 = nt0 * 16 + l15, n1 = nt1 * 16 + l15;
                        size_t rb = ((size_t)(eb0 + b) * 4 + mt) * 256;
                        latbuf[rb + n0] = f2h(fmaxf(e[mt][0][i] + eb2L[n0], 0.f));
                        latbuf[rb + n1] = f2h(fmaxf(e[mt][1][i] + eb2L[n1], 0.f));
                    }
            }
            xcd_barrier(&chunkctr[c]);
            {   // stage whole group's dt for this chunk into LDS (coalesced)
                const float* srcdt = dtbuf + (size_t)g * 2048;
                float* dstdt = &dtL[0][0];
                for (int idx = t; idx < 2048; idx += NTH) dstdt[idx] = srcdt[idx];
            }
            __syncthreads();
        }

        const int rp = s & 1, wp = rp ^ 1;
        const unsigned short* hrd = hb[rp];
        unsigned short*       hwr = hb[wp];

        const unsigned short* latp = latbuf + (r0 * 4 + cs) * 256 + lq * 8;
        const unsigned short* hp   = hrd + r0 * 512 + lq * 8;

        // ---- gate GEMM prologue: issue depth-3 A loads early so they fly
        //      under the heads phase (the heads __syncthreads drains them) ----
        half8 aF[3][4], bF[2][3];
        LDA(aF[0], 0); LDA(aF[1], 1); LDA(aF[2], 2);
        LDB(bF[0], 0); LDB(bF[1], 1);

        // ================= heads(s-1) + dp(s-1) =================
        if (s > 0) {
            f32x4 hc = fz;
            const int ka = 2 * w, kb = 2 * w + 1;
            half8 a0 = *(const half8*)(hrd + (size_t)(eb0 + l15) * 512 + ka * 32 + lq * 8);
            half8 b0 = *(const half8*)(headL + ((size_t)ka * 64 + l) * 8);
            half8 a1 = *(const half8*)(hrd + (size_t)(eb0 + l15) * 512 + kb * 32 + lq * 8);
            half8 b1 = *(const half8*)(headL + ((size_t)kb * 64 + l) * 8);
            hc = MFMA16(a0, b0, hc);
            hc = MFMA16(a1, b1, hc);
            #pragma unroll
            for (int i = 0; i < 4; ++i) sdotP[w][lq * 4 + i][l15] = hc[i];
            __syncthreads();
            if (t < BT) {
                const int b = t;
                float sd[10];
                #pragma unroll
                for (int d = 0; d < 10; ++d) {
                    float acc = 0.f;
                    #pragma unroll
                    for (int w8 = 0; w8 < 8; ++w8) acc += sdotP[w8][b][d];
                    sd[d] = acc;
                }
                const int ps = s - 1, pcc = ps & 3, ppar = (ps >> 2) & 1;
                float ax = xownL[ppar][pcc][b][0], ay = xownL[ppar][pcc][b][1];
                float az = xownL[ppar][pcc][b][2], dtv = xownL[ppar][pcc][b][3];
                float q0 = sd[0] + qb0, q1 = sd[1] + qb1;
                float q2 = sd[2] + qb2, q3 = sd[3] + qb3;
                float nrm = fmaxf(sqrtf(q0*q0 + q1*q1 + q2*q2 + q3*q3), 1e-12f);
                float qw = q0/nrm, qx = q1/nrm, qy = q2/nrm, qz = q3/nrm;
                float vx = sd[4] + vb0, vy = sd[5] + vb1, vz = sd[6] + vb2;
                float ex = sd[7] + cb0, ey = sd[8] + cb1, ez = sd[9] + cb2;
                float xx = qx*qx, yy = qy*qy, zz = qz*qz;
                float xy = qx*qy, xz = qx*qz, yz = qy*qz;
                float wxq = qw*qx, wyq = qw*qy, wzq = qw*qz;
                float aw0 = (1.f - 2.f*(yy+zz))*ax + 2.f*(xy-wzq)*ay + 2.f*(xz+wyq)*az;
                float aw1 = 2.f*(xy+wzq)*ax + (1.f - 2.f*(xx+zz))*ay + 2.f*(yz-wxq)*az;
                float aw2 = 2.f*(xz-wyq)*ax + 2.f*(yz+wxq)*ay + (1.f - 2.f*(xx+yy))*az;
                float hdt2 = 0.5f * dtv * dtv;
                dp0 += vx*dtv + aw0*hdt2 + ex;
                dp1 += vy*dtv + aw1*hdt2 + ey;
                dp2 += vz*dtv + aw2*hdt2 + ez;
            }
        }

        // ================= gate GEMM: M=512, N=48, K=768 =================
        {
            f32x4 aR[4], aZ[4], aNi[4], aNh[4];
            #pragma unroll
            for (int mt = 0; mt < 4; ++mt) {
                aR[mt] = fz; aZ[mt] = fz; aNi[mt] = fz; aNh[mt] = fz;
            }
            // depth-3 rotating A pipeline (L2-hit loads now), depth-2 B (LDS)
            #pragma unroll
            for (int kt = 0; kt < 24; ++kt) {
                DOMF(aF[kt % 3], bF[kt & 1], kt);
                if (kt < 21) LDA(aF[kt % 3], kt + 3);
                if (kt < 22) LDB(bF[kt & 1], kt + 2);
            }
            // gate nonlinearity + h_new write
            #pragma unroll
            for (int mt = 0; mt < 4; ++mt) {
                #pragma unroll
                for (int i = 0; i < 4; ++i) {
                    const int  rl  = w * 64 + mt * 16 + lq * 4 + i;   // row in group
                    const size_t row = (size_t)(g * 512) + rl;
                    float dtv = dtL[rl][cs];
                    float gr = aR[mt][i]  + bR  + dtv * wr2;
                    float gz = aZ[mt][i]  + bZ  + dtv * wz2;
                    float gi = aNi[mt][i] + bIN + dtv * wn2;
                    float gh = aNh[mt][i] + bHN;
                    float r  = 1.f / (1.f + __expf(-gr));
                    float zg = 1.f / (1.f + __expf(-gz));
                    float narg = gi + r * gh;
                    float n  = 1.f - 2.f / (__expf(2.f * narg) + 1.f);
                    float hn = (1.f - zg) * n + zg * ho[mt][i];
                    ho[mt][i] = hn;
                    hwr[row * 512 + jd] = f2h(hn);
                }
            }
        }
        xcd_barrier(&stepctr[s]);
    }
#undef LDA
#undef LDB
#undef DOMF

    // ================= epilogue: heads(T-1) + dp(T-1) + store =================
    {
        const unsigned short* hrd = hb[T_STEPS & 1];
        f32x4 hc = fz;
        const int ka = 2 * w, kb = 2 * w + 1;
        half8 a0 = *(const half8*)(hrd + (size_t)(eb0 + l15) * 512 + ka * 32 + lq * 8);
        half8 b0 = *(const half8*)(headL + ((size_t)ka * 64 + l) * 8);
        half8 a1 = *(const half8*)(hrd + (size_t)(eb0 + l15) * 512 + kb * 32 + lq * 8);
        half8 b1 = *(const half8*)(headL + ((size_t)kb * 64 + l) * 8);
        hc = MFMA16(a0, b0, hc);
        hc = MFMA16(a1, b1, hc);
        #pragma unroll
        for (int i = 0; i < 4; ++i) sdotP[w][lq * 4 + i][l15] = hc[i];
    }
    __syncthreads();
    if (t < BT) {
        const int b = t;
        float sd[10];
        #pragma unroll
        for (int d = 0; d < 10; ++d) {
            float acc = 0.f;
            #pragma unroll
            for (int w8 = 0; w8 < 8; ++w8) acc += sdotP[w8][b][d];
            sd[d] = acc;
        }
        const int pcc = (T_STEPS - 1) & 3, ppar = ((T_STEPS - 1) >> 2) & 1;
        float ax = xownL[ppar][pcc][b][0], ay = xownL[ppar][pcc][b][1];
        float az = xownL[ppar][pcc][b][2], dtv = xownL[ppar][pcc][b][3];
        float q0 = sd[0] + qb0, q1 = sd[1] + qb1;
        float q2 = sd[2] + qb2, q3 = sd[3] + qb3;
        float nrm = fmaxf(sqrtf(q0*q0 + q1*q1 + q2*q2 + q3*q3), 1e-12f);
        float qw = q0/nrm, qx = q1/nrm, qy = q2/nrm, qz = q3/nrm;
        float vx = sd[4] + vb0, vy = sd[5] + vb1, vz = sd[6] + vb2;
        float ex = sd[7] + cb0, ey = sd[8] + cb1, ez = sd[9] + cb2;
        float xx = qx*qx, yy = qy*qy, zz = qz*qz;
        float xy = qx*qy, xz = qx*qz, yz = qy*qz;
        float wxq = qw*qx, wyq = qw*qy, wzq = qw*qz;
        float aw0 = (1.f - 2.f*(yy+zz))*ax + 2.f*(xy-wzq)*ay + 2.f*(xz+wyq)*az;
        float aw1 = 2.f*(xy+wzq)*ax + (1.f - 2.f*(xx+zz))*ay + 2.f*(yz-wxq)*az;
        float aw2 = 2.f*(xz-wyq)*ax + 2.f*(yz+wxq)*ay + (1.f - 2.f*(xx+yy))*az;
        float hdt2 = 0.5f * dtv * dtv;
        dp0 += vx*dtv + aw0*hdt2 + ex;
        dp1 += vy*dtv + aw1*hdt2 + ey;
        dp2 += vz*dtv + aw2*hdt2 + ez;
        out[(size_t)(eb0 + b) * 3 + 0] = dp0;
        out[(size_t)(eb0 + b) * 3 + 1] = dp1;
        out[(size_t)(eb0 + b) * 3 + 2] = dp2;
    }
}

extern "C" void kernel_launch(void* const* d_in, const int* in_sizes, int n_in,
                              void* d_out, int out_size, void* d_ws, size_t ws_size,
                              hipStream_t stream) {
    const float* x      = (const float*)d_in[0];
    const float* h0     = (const float*)d_in[1];
    const float* enc_w1 = (const float*)d_in[2];
    const float* enc_b1 = (const float*)d_in[3];
    const float* enc_w2 = (const float*)d_in[4];
    const float* enc_b2 = (const float*)d_in[5];
    const float* w_ih   = (const float*)d_in[6];
    const float* w_hh   = (const float*)d_in[7];
    const float* b_ih   = (const float*)d_in[8];
    const float* b_hh   = (const float*)d_in[9];
    const float* q_w    = (const float*)d_in[10];
    const float* q_b    = (const float*)d_in[11];
    const float* v_w    = (const float*)d_in[12];
    const float* v_b    = (const float*)d_in[13];
    const float* c_w    = (const float*)d_in[14];
    const float* c_b    = (const float*)d_in[15];
    unsigned char* ws = (unsigned char*)d_ws;
    float* out = (float*)d_out;

    hipLaunchKernelGGL(pack_kernel, dim3(2048), dim3(256), 0, stream,
                       enc_w1, enc_w2, w_ih, w_hh, b_ih, b_hh, q_w, v_w, c_w, h0, ws);

    void* args[] = { (void*)&x, (void*)&h0, (void*)&enc_b1, (void*)&enc_b2,
                     (void*)&q_b, (void*)&v_b, (void*)&c_b, (void*)&ws, (void*)&out };
    (void)hipLaunchCooperativeKernel((void*)imu_coop_kernel, dim3(256), dim3(NTH),
                                     args, 0, stream);
}

// Round 4
// 12064.577 us; speedup vs baseline: 2.2683x; 1.2911x over previous
//
#include <hip/hip_runtime.h>
#include <math.h>

#define T_STEPS 512
#define IN_DIM  17
#define HID     512
#define LAT     256
#define BT      16
#define NTH     512
#define CHUNK   4

typedef __attribute__((ext_vector_type(8))) _Float16 half8;
typedef __attribute__((ext_vector_type(4))) float    f32x4;

// ---------------- workspace layout (byte offsets, 16B-aligned) ----------
// hbuf0/1 : h double buffer, SLICE-MAJOR: [8 g][32 ss][512 row][16] fp16
//           (each block owns contiguous 16KB per slice -> full-line writes
//            from ONE CU -> write-combine works -> lines stay in L2)
#define OFF_HB0   0
#define OFF_HB1   4194304
#define OFF_LAT   8388608
#define OFF_WG    16777216
#define OFF_W2P   19136512
#define OFF_W1P   19267584
#define OFF_HEADP 19283968
#define OFF_W256  19300352
#define OFF_BCOMB 19306496
#define OFF_BHN   19312640
#define OFF_DT    19314688
#define OFF_CTR   19380224
// ctr region: stepctr uint[8][512] + chunkctr uint[8][128] + ticket uint[8]

static __device__ inline unsigned short f2h(float f) {
    union { _Float16 h; unsigned short u; } cv;
    cv.h = (_Float16)f;
    return cv.u;
}

__global__ void pack_kernel(const float* __restrict__ enc_w1,
                            const float* __restrict__ enc_w2,
                            const float* __restrict__ w_ih,
                            const float* __restrict__ w_hh,
                            const float* __restrict__ b_ih,
                            const float* __restrict__ b_hh,
                            const float* __restrict__ q_w,
                            const float* __restrict__ v_w,
                            const float* __restrict__ c_w,
                            const float* __restrict__ h0,
                            unsigned char* __restrict__ ws) {
    unsigned short* wgP   = (unsigned short*)(ws + OFF_WG);
    unsigned short* w2P   = (unsigned short*)(ws + OFF_W2P);
    unsigned short* w1P   = (unsigned short*)(ws + OFF_W1P);
    unsigned short* headP = (unsigned short*)(ws + OFF_HEADP);
    unsigned short* hb0   = (unsigned short*)(ws + OFF_HB0);
    float* w256  = (float*)(ws + OFF_W256);
    float* bcomb = (float*)(ws + OFF_BCOMB);
    float* bhn   = (float*)(ws + OFF_BHN);
    unsigned int* ctr = (unsigned int*)(ws + OFF_CTR);

    const int tid = blockIdx.x * blockDim.x + threadIdx.x;
    const int stride = gridDim.x * blockDim.x;

    for (int idx = tid; idx < 32 * 24 * 3 * 64 * 8; idx += stride) {     // wgP
        int j = idx & 7, l = (idx >> 3) & 63;
        int r = idx >> 9;
        int g = r % 3; r /= 3;
        int kt = r % 24; int s = r / 24;
        int row = g * 512 + s * 16 + (l & 15);
        int kk  = ((l >> 4) & 3) * 8 + j;
        float v;
        if (kt < 8) v = w_ih[(size_t)row * 257 + (kt * 32 + kk)];
        else        v = w_hh[(size_t)row * 512 + ((kt - 8) * 32 + kk)];
        wgP[idx] = f2h(v);
    }
    for (int idx = tid; idx < 16 * 8 * 64 * 8; idx += stride) {          // w2P
        int j = idx & 7, l = (idx >> 3) & 63, kt = (idx >> 9) & 7, nt = idx >> 12;
        int n = nt * 16 + (l & 15);
        int k = kt * 32 + ((l >> 4) & 3) * 8 + j;
        w2P[idx] = f2h(enc_w2[(size_t)n * 256 + k]);
    }
    for (int idx = tid; idx < 16 * 64 * 8; idx += stride) {              // w1P
        int j = idx & 7, l = (idx >> 3) & 63, nt = idx >> 9;
        int n = nt * 16 + (l & 15);
        int k = ((l >> 4) & 3) * 8 + j;
        w1P[idx] = (k < IN_DIM) ? f2h(enc_w1[(size_t)n * IN_DIM + k]) : (unsigned short)0;
    }
    for (int idx = tid; idx < 16 * 64 * 8; idx += stride) {              // headP
        int j = idx & 7, l = (idx >> 3) & 63, kt = idx >> 9;
        int d = l & 15;
        int k = kt * 32 + ((l >> 4) & 3) * 8 + j;
        float v = 0.f;
        if (d < 4)       v = q_w[(size_t)d * HID + k];
        else if (d < 7)  v = v_w[(size_t)(d - 4) * HID + k];
        else if (d < 10) v = c_w[(size_t)(d - 7) * HID + k];
        headP[idx] = f2h(v);
    }
    for (int idx = tid; idx < 1536; idx += stride) {
        w256[idx]  = w_ih[(size_t)idx * 257 + 256];
        bcomb[idx] = (idx < 1024) ? (b_ih[idx] + b_hh[idx]) : b_ih[idx];
    }
    for (int idx = tid; idx < 512; idx += stride) bhn[idx] = b_hh[1024 + idx];
    for (int idx = tid; idx < 4096 * 512; idx += stride) {               // h0 -> hbuf0 (slice-major)
        int c  = idx & 15;
        int r  = (idx >> 4) & 511;
        int sg = idx >> 13;            // g*32 + ss
        int gg = sg >> 5, ss = sg & 31;
        hb0[idx] = f2h(h0[((size_t)(gg * 512 + r)) * 512 + ss * 16 + c]);
    }
    for (int idx = tid; idx < 5128; idx += stride) ctr[idx] = 0;         // barriers + tickets
}

#define MFMA16(a, b, c) __builtin_amdgcn_mfma_f32_16x16x32_f16((a), (b), (c), 0, 0, 0)

// ---- split 32-block XCD-local barrier: arrive (non-blocking) / wait ----
// Groups are pinned to one physical XCD (g = HW_REG_XCC_ID), so the XCD L2 is
// the coherence point. arrive: __syncthreads drains all waves' stores to L2,
// then one relaxed agent-scope add. wait: poll relaxed, then L1-only inv.
// Watchdog: a genuine deadlock (e.g. anomalous block->XCD distribution) breaks
// out after ~1e8 spins so the run FINISHES (wrong) and yields diagnostics
// instead of killing the container.
static __device__ inline void bar_arrive(unsigned int* slot) {
    __syncthreads();
    if (threadIdx.x == 0)
        __hip_atomic_fetch_add(slot, 1u, __ATOMIC_RELAXED, __HIP_MEMORY_SCOPE_AGENT);
}
static __device__ inline void bar_wait(unsigned int* slot) {
    if (threadIdx.x == 0) {
        unsigned int spins = 0;
        while (__hip_atomic_load(slot, __ATOMIC_RELAXED, __HIP_MEMORY_SCOPE_AGENT) < 32u) {
            __builtin_amdgcn_s_sleep(2);
            if (++spins > 100000000u) break;   // watchdog: never hit in normal runs
        }
    }
    __syncthreads();
    asm volatile("buffer_inv sc0" ::: "memory");   // per-wave L1 invalidate
}
static __device__ inline void xcd_barrier(unsigned int* slot) {
    bar_arrive(slot);
    bar_wait(slot);
}

__global__ __launch_bounds__(NTH, 2)
void imu_coop_kernel(const float* __restrict__ x,
                     const float* __restrict__ h0,
                     const float* __restrict__ enc_b1,
                     const float* __restrict__ enc_b2,
                     const float* __restrict__ q_b,
                     const float* __restrict__ v_b,
                     const float* __restrict__ c_b,
                     unsigned char* __restrict__ ws,
                     float* __restrict__ out)
{
    __shared__ __align__(16) unsigned short wgL[24 * 3 * 64 * 8];   // 73,728 B
    __shared__ __align__(16) unsigned short headL[16 * 64 * 8];     // 16,384 B
    __shared__ __align__(16) unsigned short xbf64[64][32];          //  4,096 B
    __shared__ __align__(16) unsigned short z1bf64[64][264];        // 33,792 B
    __shared__ __align__(16) float          sdotP[8][16][17];       //  8,704 B
    __shared__ float eb1L[256], eb2L[256];                          //  2,048 B
    __shared__ float dtL[512][4];                                   //  8,192 B
    __shared__ float xownL[2][4][16][4];                            //  2,048 B
    __shared__ int   s_slS;

    unsigned short* hb[2] = { (unsigned short*)(ws + OFF_HB0),
                              (unsigned short*)(ws + OFF_HB1) };
    unsigned short*       latbuf = (unsigned short*)(ws + OFF_LAT);
    const unsigned short* wgP    = (const unsigned short*)(ws + OFF_WG);
    const unsigned short* w2P    = (const unsigned short*)(ws + OFF_W2P);
    const unsigned short* w1P    = (const unsigned short*)(ws + OFF_W1P);
    const unsigned short* headP  = (const unsigned short*)(ws + OFF_HEADP);
    const float* w256g = (const float*)(ws + OFF_W256);
    const float* bcmg  = (const float*)(ws + OFF_BCOMB);
    const float* bhng  = (const float*)(ws + OFF_BHN);
    float* dtbuf = (float*)(ws + OFF_DT);

    const int t    = threadIdx.x;
    const int w    = t >> 6;
    const int l    = t & 63;
    const int l15  = l & 15;
    const int lq   = (l >> 4) & 3;
    const int lqh  = lq >> 1;            // which of the two 16-col slices in a 32-K tile
    const int c8   = (lq & 1) * 8;       // col offset inside the slice

    // ---- XCD-local self-assignment: group = physical XCD, slice = ticket ----
    // LDS ~149KB forces 1 block/CU; cooperative launch co-residency on 256 CUs
    // => exactly 32 blocks per XCD, so tickets 0..31 and groups are XCD-local
    // BY CONSTRUCTION (no assumption about blockIdx->XCD mapping).
    unsigned int xcc;
    asm volatile("s_getreg_b32 %0, hwreg(HW_REG_XCC_ID)" : "=s"(xcc));
    const int g = (int)(xcc & 7u);
    if (t == 0) {
        unsigned int* tk = (unsigned int*)(ws + OFF_CTR) + 5120 + g;
        s_slS = (int)(__hip_atomic_fetch_add(tk, 1u, __ATOMIC_RELAXED,
                                             __HIP_MEMORY_SCOPE_AGENT) & 31u);
    }
    __syncthreads();
    const int s_sl = s_slS;                      // gate N-slice 0..31
    const int eb0  = g * 512 + s_sl * 16;        // encoder/heads batch rows

    unsigned int* stepctr  = (unsigned int*)(ws + OFF_CTR) + (size_t)g * 512;
    unsigned int* chunkctr = (unsigned int*)(ws + OFF_CTR + 16384) + (size_t)g * 128;

    const f32x4 fz = {0.f, 0.f, 0.f, 0.f};

    // ---- one-time init ----
    {
        const uint4* src = (const uint4*)(wgP + (size_t)s_sl * (24 * 3 * 64 * 8));
        uint4* dst = (uint4*)wgL;
        for (int i = t; i < 24 * 3 * 64; i += NTH) dst[i] = src[i];
    }
    {
        const uint4* src = (const uint4*)headP;
        uint4* dst = (uint4*)headL;
        for (int i = t; i < 16 * 64; i += NTH) dst[i] = src[i];
    }
    for (int idx = t; idx < 256; idx += NTH) { eb1L[idx] = enc_b1[idx]; eb2L[idx] = enc_b2[idx]; }
    for (int idx = t; idx < 64 * 32; idx += NTH) xbf64[idx >> 5][idx & 31] = 0;

    const float qb0 = q_b[0], qb1 = q_b[1], qb2 = q_b[2], qb3 = q_b[3];
    const float vb0 = v_b[0], vb1 = v_b[1], vb2 = v_b[2];
    const float cb0 = c_b[0], cb1 = c_b[1], cb2 = c_b[2];

    const int jd = s_sl * 16 + l15;              // owned gate/h dim
    const float bR  = bcmg[jd],        bZ  = bcmg[512 + jd];
    const float bIN = bcmg[1024 + jd], bHN = bhng[jd];
    const float wr2 = w256g[jd], wz2 = w256g[512 + jd], wn2 = w256g[1024 + jd];

    float ho[4][4];                              // h_old fp32 in regs
    #pragma unroll
    for (int mt = 0; mt < 4; ++mt)
        #pragma unroll
        for (int i = 0; i < 4; ++i)
            ho[mt][i] = h0[(size_t)(g * 512 + w * 64 + mt * 16 + lq * 4 + i) * HID + jd];

    float dp0 = 0.f, dp1 = 0.f, dp2 = 0.f;
    __syncthreads();

    const size_t r0 = (size_t)(g * 512 + w * 64) + l15;   // latbuf A-frag row base

#define LDA_L(dst, ktv)                                                         \
            { _Pragma("unroll")                                                 \
              for (int mt = 0; mt < 4; ++mt)                                    \
                  dst[mt] = *(const half8*)(latp + (size_t)mt * (16 * 4 * 256) + (ktv) * 32); }
#define LDA_H(dst, ktv)                                                         \
            { _Pragma("unroll")                                                 \
              for (int mt = 0; mt < 4; ++mt)                                    \
                  dst[mt] = *(const half8*)(hA + (size_t)((ktv) - 8) * 16384 + mt * 256); }
#define LDB(dst, ktv)                                                           \
            { _Pragma("unroll")                                                 \
              for (int gg = 0; gg < 3; ++gg)                                    \
                  dst[gg] = *(const half8*)&wgL[(((ktv) * 3 + gg) * 64 + l) * 8]; }
#define DOMF_L(A, B)                                                            \
            { _Pragma("unroll")                                                 \
              for (int mt = 0; mt < 4; ++mt) {                                  \
                  aR[mt]  = MFMA16(A[mt], B[0], aR[mt]);                        \
                  aZ[mt]  = MFMA16(A[mt], B[1], aZ[mt]);                        \
                  aNi[mt] = MFMA16(A[mt], B[2], aNi[mt]); } }
#define DOMF_H(A, B)                                                            \
            { _Pragma("unroll")                                                 \
              for (int mt = 0; mt < 4; ++mt) {                                  \
                  aR[mt]  = MFMA16(A[mt], B[0], aR[mt]);                        \
                  aZ[mt]  = MFMA16(A[mt], B[1], aZ[mt]);                        \
                  aNh[mt] = MFMA16(A[mt], B[2], aNh[mt]); } }

    for (int s = 0; s < T_STEPS; ++s) {
        const int cs = s & 3;
        const int rp = s & 1, wp = rp ^ 1;
        const unsigned short* hgx = hb[rp] + (size_t)g * 262144;              // read base
        unsigned short*       hwx = hb[wp] + (size_t)g * 262144 + (size_t)s_sl * 8192;

        // ================= chunk pre-phase, once per 4 steps =================
        if (cs == 0) {
            // must wait for step s-1 BEFORE overwriting latbuf/dtbuf slots
            if (s > 0) bar_wait(&stepctr[s - 1]);
            const int c = s >> 2;
            for (int idx = t; idx < 17 * 16 * CHUNK; idx += NTH) {
                int k = idx % 17, rem = idx / 17;
                int b = rem & 15, cc = rem >> 4;
                float v = x[((size_t)(eb0 + b) * T_STEPS + (c * 4 + cc)) * IN_DIM + k];
                xbf64[cc * 16 + b][k] = f2h(v);
                if (k < 3) xownL[c & 1][cc][b][k] = v;
                if (k == 16) {
                    dtbuf[(size_t)(eb0 + b) * 4 + cc] = v;
                    xownL[c & 1][cc][b][3] = v;
                }
            }
            __syncthreads();
            {   // E1: M=64 (16 batch x 4 steps), N=256, K=32
                const int nt0 = 2 * w, nt1 = 2 * w + 1;
                half8 bv0 = *(const half8*)(w1P + ((size_t)nt0 * 64 + l) * 8);
                half8 bv1 = *(const half8*)(w1P + ((size_t)nt1 * 64 + l) * 8);
                f32x4 e[4][2];
                #pragma unroll
                for (int mt = 0; mt < 4; ++mt) {
                    half8 av = *(const half8*)&xbf64[mt * 16 + l15][lq * 8];
                    e[mt][0] = MFMA16(av, bv0, fz);
                    e[mt][1] = MFMA16(av, bv1, fz);
                }
                __syncthreads();
                #pragma unroll
                for (int mt = 0; mt < 4; ++mt)
                    #pragma unroll
                    for (int i = 0; i < 4; ++i) {
                        int m64 = mt * 16 + lq * 4 + i;
                        int n0 = nt0 * 16 + l15, n1 = nt1 * 16 + l15;
                        z1bf64[m64][n0] = f2h(fmaxf(e[mt][0][i] + eb1L[n0], 0.f));
                        z1bf64[m64][n1] = f2h(fmaxf(e[mt][1][i] + eb1L[n1], 0.f));
                    }
            }
            __syncthreads();
            {   // E2: M=64, N=256, K=256 -> latbuf (global)
                const int nt0 = 2 * w, nt1 = 2 * w + 1;
                f32x4 e[4][2];
                #pragma unroll
                for (int mt = 0; mt < 4; ++mt) { e[mt][0] = fz; e[mt][1] = fz; }
                #pragma unroll
                for (int kt = 0; kt < 8; ++kt) {
                    half8 bv0 = *(const half8*)(w2P + ((size_t)(nt0 * 8 + kt) * 64 + l) * 8);
                    half8 bv1 = *(const half8*)(w2P + ((size_t)(nt1 * 8 + kt) * 64 + l) * 8);
                    #pragma unroll
                    for (int mt = 0; mt < 4; ++mt) {
                        half8 av = *(const half8*)&z1bf64[mt * 16 + l15][kt * 32 + lq * 8];
                        e[mt][0] = MFMA16(av, bv0, e[mt][0]);
                        e[mt][1] = MFMA16(av, bv1, e[mt][1]);
                    }
                }
                #pragma unroll
                for (int mt = 0; mt < 4; ++mt)
                    #pragma unroll
                    for (int i = 0; i < 4; ++i) {
                        int b = lq * 4 + i;      // batch-in-16 ; cc = mt
                        int n0 = nt0 * 16 + l15, n1 = nt1 * 16 + l15;
                        size_t rb = ((size_t)(eb0 + b) * 4 + mt) * 256;
                        latbuf[rb + n0] = f2h(fmaxf(e[mt][0][i] + eb2L[n0], 0.f));
                        latbuf[rb + n1] = f2h(fmaxf(e[mt][1][i] + eb2L[n1], 0.f));
                    }
            }
            xcd_barrier(&chunkctr[c]);
            {   // stage whole group's dt for this chunk into LDS (coalesced)
                const float* srcdt = dtbuf + (size_t)g * 2048;
                float* dstdt = &dtL[0][0];
                for (int idx = t; idx < 2048; idx += NTH) dstdt[idx] = srcdt[idx];
            }
            __syncthreads();
        }

        // ---- accumulators ----
        f32x4 aR[4], aZ[4], aNi[4], aNh[4];
        #pragma unroll
        for (int mt = 0; mt < 4; ++mt) { aR[mt] = fz; aZ[mt] = fz; aNi[mt] = fz; aNh[mt] = fz; }

        // ========== lat part of gate GEMM (kt 0..7): chunk-stable, no h dep ==========
        {
            const unsigned short* latp = latbuf + (r0 * 4 + cs) * 256 + lq * 8;
            half8 aF[3][4], bF[2][3];
            LDA_L(aF[0], 0); LDA_L(aF[1], 1); LDA_L(aF[2], 2);
            LDB(bF[0], 0); LDB(bF[1], 1);
            #pragma unroll
            for (int kt = 0; kt < 8; ++kt) {
                DOMF_L(aF[kt % 3], bF[kt & 1]);
                if (kt < 5) LDA_L(aF[kt % 3], kt + 3);
                if (kt < 6) LDB(bF[kt & 1], kt + 2);
            }
        }

        // ========== wait for h(s-1) (absorbs skew under the lat work above) ==========
        if (cs != 0 && s > 0) bar_wait(&stepctr[s - 1]);

        // ---- h-part prologue: issue depth-3 A loads so they fly under heads ----
        const unsigned short* hA = hgx + (size_t)lqh * 8192
                                       + (size_t)(w * 64 + l15) * 16 + c8;
        half8 aF[3][4], bF[2][3];
        LDA_H(aF[0], 8); LDA_H(aF[1], 9); LDA_H(aF[2], 10);
        LDB(bF[0], 8); LDB(bF[1], 9);

        // ================= heads(s-1) + dp(s-1) =================
        if (s > 0) {
            f32x4 hc = fz;
            const int ka = 2 * w, kb = 2 * w + 1;
            const unsigned short* hH = hgx + (size_t)(s_sl * 16 + l15) * 16 + c8;
            half8 a0 = *(const half8*)(hH + (size_t)(2 * ka + lqh) * 8192);
            half8 b0 = *(const half8*)(headL + ((size_t)ka * 64 + l) * 8);
            half8 a1 = *(const half8*)(hH + (size_t)(2 * kb + lqh) * 8192);
            half8 b1 = *(const half8*)(headL + ((size_t)kb * 64 + l) * 8);
            hc = MFMA16(a0, b0, hc);
            hc = MFMA16(a1, b1, hc);
            #pragma unroll
            for (int i = 0; i < 4; ++i) sdotP[w][lq * 4 + i][l15] = hc[i];
            __syncthreads();
            if (t < BT) {
                const int b = t;
                float sd[10];
                #pragma unroll
                for (int d = 0; d < 10; ++d) {
                    float acc = 0.f;
                    #pragma unroll
                    for (int w8 = 0; w8 < 8; ++w8) acc += sdotP[w8][b][d];
                    sd[d] = acc;
                }
                const int ps = s - 1, pcc = ps & 3, ppar = (ps >> 2) & 1;
                float ax = xownL[ppar][pcc][b][0], ay = xownL[ppar][pcc][b][1];
                float az = xownL[ppar][pcc][b][2], dtv = xownL[ppar][pcc][b][3];
                float q0 = sd[0] + qb0, q1 = sd[1] + qb1;
                float q2 = sd[2] + qb2, q3 = sd[3] + qb3;
                float nrm = fmaxf(sqrtf(q0*q0 + q1*q1 + q2*q2 + q3*q3), 1e-12f);
                float qw = q0/nrm, qx = q1/nrm, qy = q2/nrm, qz = q3/nrm;
                float vx = sd[4] + vb0, vy = sd[5] + vb1, vz = sd[6] + vb2;
                float ex = sd[7] + cb0, ey = sd[8] + cb1, ez = sd[9] + cb2;
                float xx = qx*qx, yy = qy*qy, zz = qz*qz;
                float xy = qx*qy, xz = qx*qz, yz = qy*qz;
                float wxq = qw*qx, wyq = qw*qy, wzq = qw*qz;
                float aw0 = (1.f - 2.f*(yy+zz))*ax + 2.f*(xy-wzq)*ay + 2.f*(xz+wyq)*az;
                float aw1 = 2.f*(xy+wzq)*ax + (1.f - 2.f*(xx+zz))*ay + 2.f*(yz-wxq)*az;
                float aw2 = 2.f*(xz-wyq)*ax + 2.f*(yz+wxq)*ay + (1.f - 2.f*(xx+yy))*az;
                float hdt2 = 0.5f * dtv * dtv;
                dp0 += vx*dtv + aw0*hdt2 + ex;
                dp1 += vy*dtv + aw1*hdt2 + ey;
                dp2 += vz*dtv + aw2*hdt2 + ez;
            }
        }

        // ========== h part of gate GEMM (kt 8..23) ==========
        #pragma unroll
        for (int k2 = 0; k2 < 16; ++k2) {
            DOMF_H(aF[k2 % 3], bF[k2 & 1]);
            if (k2 < 13) LDA_H(aF[k2 % 3], k2 + 11);
            if (k2 < 14) LDB(bF[k2 & 1], k2 + 10);
        }

        // ---- gate nonlinearity + h_new write (slice-major, coalesced) ----
        #pragma unroll
        for (int mt = 0; mt < 4; ++mt) {
            #pragma unroll
            for (int i = 0; i < 4; ++i) {
                const int rl = w * 64 + mt * 16 + lq * 4 + i;   // row in group
                float dtv = dtL[rl][cs];
                float gr = aR[mt][i]  + bR  + dtv * wr2;
                float gz = aZ[mt][i]  + bZ  + dtv * wz2;
                float gi = aNi[mt][i] + bIN + dtv * wn2;
                float gh = aNh[mt][i] + bHN;
                float r  = 1.f / (1.f + __expf(-gr));
                float zg = 1.f / (1.f + __expf(-gz));
                float narg = gi + r * gh;
                float n  = 1.f - 2.f / (__expf(2.f * narg) + 1.f);
                float hn = (1.f - zg) * n + zg * ho[mt][i];
                ho[mt][i] = hn;
                hwx[rl * 16 + l15] = f2h(hn);
            }
        }
        bar_arrive(&stepctr[s]);
    }
#undef LDA_L
#undef LDA_H
#undef LDB
#undef DOMF_L
#undef DOMF_H

    // ================= epilogue: heads(T-1) + dp(T-1) + store =================
    bar_wait(&stepctr[T_STEPS - 1]);
    {
        const unsigned short* hgx = hb[T_STEPS & 1] + (size_t)g * 262144;
        f32x4 hc = fz;
        const int ka = 2 * w, kb = 2 * w + 1;
        const unsigned short* hH = hgx + (size_t)(s_sl * 16 + l15) * 16 + c8;
        half8 a0 = *(const half8*)(hH + (size_t)(2 * ka + lqh) * 8192);
        half8 b0 = *(const half8*)(headL + ((size_t)ka * 64 + l) * 8);
        half8 a1 = *(const half8*)(hH + (size_t)(2 * kb + lqh) * 8192);
        half8 b1 = *(const half8*)(headL + ((size_t)kb * 64 + l) * 8);
        hc = MFMA16(a0, b0, hc);
        hc = MFMA16(a1, b1, hc);
        #pragma unroll
        for (int i = 0; i < 4; ++i) sdotP[w][lq * 4 + i][l15] = hc[i];
    }
    __syncthreads();
    if (t < BT) {
        const int b = t;
        float sd[10];
        #pragma unroll
        for (int d = 0; d < 10; ++d) {
            float acc = 0.f;
            #pragma unroll
            for (int w8 = 0; w8 < 8; ++w8) acc += sdotP[w8][b][d];
            sd[d] = acc;
        }
        const int pcc = (T_STEPS - 1) & 3, ppar = ((T_STEPS - 1) >> 2) & 1;
        float ax = xownL[ppar][pcc][b][0], ay = xownL[ppar][pcc][b][1];
        float az = xownL[ppar][pcc][b][2], dtv = xownL[ppar][pcc][b][3];
        float q0 = sd[0] + qb0, q1 = sd[1] + qb1;
        float q2 = sd[2] + qb2, q3 = sd[3] + qb3;
        float nrm = fmaxf(sqrtf(q0*q0 + q1*q1 + q2*q2 + q3*q3), 1e-12f);
        float qw = q0/nrm, qx = q1/nrm, qy = q2/nrm, qz = q3/nrm;
        float vx = sd[4] + vb0, vy = sd[5] + vb1, vz = sd[6] + vb2;
        float ex = sd[7] + cb0, ey = sd[8] + cb1, ez = sd[9] + cb2;
        float xx = qx*qx, yy = qy*qy, zz = qz*qz;
        float xy = qx*qy, xz = qx*qz, yz = qy*qz;
        float wxq = qw*qx, wyq = qw*qy, wzq = qw*qz;
        float aw0 = (1.f - 2.f*(yy+zz))*ax + 2.f*(xy-wzq)*ay + 2.f*(xz+wyq)*az;
        float aw1 = 2.f*(xy+wzq)*ax + (1.f - 2.f*(xx+zz))*ay + 2.f*(yz-wxq)*az;
        float aw2 = 2.f*(xz-wyq)*ax + 2.f*(yz+wxq)*ay + (1.f - 2.f*(xx+yy))*az;
        float hdt2 = 0.5f * dtv * dtv;
        dp0 += vx*dtv + aw0*hdt2 + ex;
        dp1 += vy*dtv + aw1*hdt2 + ey;
        dp2 += vz*dtv + aw2*hdt2 + ez;
        out[(size_t)(eb0 + b) * 3 + 0] = dp0;
        out[(size_t)(eb0 + b) * 3 + 1] = dp1;
        out[(size_t)(eb0 + b) * 3 + 2] = dp2;
    }
}

extern "C" void kernel_launch(void* const* d_in, const int* in_sizes, int n_in,
                              void* d_out, int out_size, void* d_ws, size_t ws_size,
                              hipStream_t stream) {
    const float* x      = (const float*)d_in[0];
    const float* h0     = (const float*)d_in[1];
    const float* enc_w1 = (const float*)d_in[2];
    const float* enc_b1 = (const float*)d_in[3];
    const float* enc_w2 = (const float*)d_in[4];
    const float* enc_b2 = (const float*)d_in[5];
    const float* w_ih   = (const float*)d_in[6];
    const float* w_hh   = (const float*)d_in[7];
    const float* b_ih   = (const float*)d_in[8];
    const float* b_hh   = (const float*)d_in[9];
    const float* q_w    = (const float*)d_in[10];
    const float* q_b    = (const float*)d_in[11];
    const float* v_w    = (const float*)d_in[12];
    const float* v_b    = (const float*)d_in[13];
    const float* c_w    = (const float*)d_in[14];
    const float* c_b    = (const float*)d_in[15];
    unsigned char* ws = (unsigned char*)d_ws;
    float* out = (float*)d_out;

    hipLaunchKernelGGL(pack_kernel, dim3(2048), dim3(256), 0, stream,
                       enc_w1, enc_w2, w_ih, w_hh, b_ih, b_hh, q_w, v_w, c_w, h0, ws);

    void* args[] = { (void*)&x, (void*)&h0, (void*)&enc_b1, (void*)&enc_b2,
                     (void*)&q_b, (void*)&v_b, (void*)&c_b, (void*)&ws, (void*)&out };
    (void)hipLaunchCooperativeKernel((void*)imu_coop_kernel, dim3(256), dim3(NTH),
                                     args, 0, stream);
}